// Round 1
// baseline (1227.272 us; speedup 1.0000x reference)
//
#include <hip/hip_runtime.h>
#include <math.h>

// Problem: B=32, N=1024 Sinkhorn (20 iters) on gumbel noise.
// KEY FACT: scalar_scores (scores@W+b) broadcast along axis 2 cancels under the
// FIRST row-logsumexp subtraction -> inputs 0..2 are dead. Output = exp(g + t_i + v_j).
#define BB 32
#define NN 1024

// t[b,i] = -logsumexp_j( g[b,i,j] + (USE_V ? v[b,j] : 0) )
template<bool USE_V>
__global__ __launch_bounds__(256) void row_step(const float* __restrict__ g,
                                                const float* __restrict__ v,
                                                float* __restrict__ t) {
    const int wave = threadIdx.x >> 6;
    const int lane = threadIdx.x & 63;
    const int row  = blockIdx.x * 4 + wave;        // b*N + i, 0..32767
    const int b    = row >> 10;
    const float4* grow = (const float4*)(g + ((size_t)row << 10));
    const float4* vrow = (const float4*)(v + ((size_t)b << 10));

    float x[16];
    #pragma unroll
    for (int k = 0; k < 4; k++) {
        float4 gg = grow[lane + 64 * k];
        if (USE_V) {
            float4 vv = vrow[lane + 64 * k];
            x[4*k+0] = gg.x + vv.x; x[4*k+1] = gg.y + vv.y;
            x[4*k+2] = gg.z + vv.z; x[4*k+3] = gg.w + vv.w;
        } else {
            x[4*k+0] = gg.x; x[4*k+1] = gg.y; x[4*k+2] = gg.z; x[4*k+3] = gg.w;
        }
    }
    float m = -INFINITY;
    #pragma unroll
    for (int k = 0; k < 16; k++) m = fmaxf(m, x[k]);
    #pragma unroll
    for (int off = 32; off > 0; off >>= 1) m = fmaxf(m, __shfl_xor(m, off));
    float s = 0.f;
    #pragma unroll
    for (int k = 0; k < 16; k++) s += __expf(x[k] - m);
    #pragma unroll
    for (int off = 32; off > 0; off >>= 1) s += __shfl_xor(s, off);
    if (lane == 0) t[row] = -(m + __logf(s));
}

// v[b,j] = -logsumexp_i( g[b,i,j] + t[b,i] )
__global__ __launch_bounds__(256) void col_step(const float* __restrict__ g,
                                                const float* __restrict__ t,
                                                float* __restrict__ v) {
    const int b    = blockIdx.x >> 4;          // 512 blocks: b * 16 tiles
    const int tile = blockIdx.x & 15;
    const int tx   = threadIdx.x & 63;         // column within tile
    const int ty   = threadIdx.x >> 6;         // row-group (wave id), 0..3
    const int j    = tile * 64 + tx;
    const float* gp = g + ((size_t)b << 20) + j;   // g[b, 0, j]
    const float* tp = t + (b << 10);

    float m = -INFINITY, s = 0.f;
    for (int it = 0; it < 256; it += 8) {
        float xv[8];
        #pragma unroll
        for (int u = 0; u < 8; u++) {
            int i = ((it + u) << 2) + ty;      // i = 4*(it+u) + ty
            xv[u] = gp[(size_t)i << 10] + tp[i];
        }
        #pragma unroll
        for (int u = 0; u < 8; u++) {
            float nm = fmaxf(m, xv[u]);
            s = s * __expf(m - nm) + __expf(xv[u] - nm);
            m = nm;
        }
    }

    __shared__ float sm[4][64];
    __shared__ float ss[4][64];
    sm[ty][tx] = m; ss[ty][tx] = s;
    __syncthreads();
    if (ty == 0) {
        float M = sm[0][tx], S = ss[0][tx];
        #pragma unroll
        for (int k = 1; k < 4; k++) {
            float mk = sm[k][tx], sk = ss[k][tx];
            float nm = fmaxf(M, mk);
            S = S * __expf(M - nm) + sk * __expf(mk - nm);
            M = nm;
        }
        v[(b << 10) + j] = -(M + __logf(S));
    }
}

// out = exp(g + t_i + v_j)
__global__ __launch_bounds__(256) void finalize_k(const float* __restrict__ g,
                                                  const float* __restrict__ t,
                                                  const float* __restrict__ v,
                                                  float* __restrict__ out) {
    const size_t idx4 = (size_t)blockIdx.x * 256 + threadIdx.x;  // float4 index
    const size_t base = idx4 << 2;                               // element index
    const int row = (int)(base >> 10);    // b*N + i
    const int b   = row >> 10;
    const int j   = (int)(base & 1023);
    const float ti = t[row];
    float4 gg = ((const float4*)g)[idx4];
    float4 vv = ((const float4*)(v + ((size_t)b << 10)))[j >> 2];
    float4 o;
    o.x = __expf(gg.x + ti + vv.x);
    o.y = __expf(gg.y + ti + vv.y);
    o.z = __expf(gg.z + ti + vv.z);
    o.w = __expf(gg.w + ti + vv.w);
    ((float4*)out)[idx4] = o;
}

extern "C" void kernel_launch(void* const* d_in, const int* in_sizes, int n_in,
                              void* d_out, int out_size, void* d_ws, size_t ws_size,
                              hipStream_t stream) {
    // d_in[0]=scores, d_in[1]=W, d_in[2]=b : DEAD (cancel under first row-lse).
    const float* g = (const float*)d_in[3];
    float* out = (float*)d_out;
    float* t = (float*)d_ws;            // B*N floats
    float* v = t + BB * NN;             // B*N floats  (512 KB total ws use)

    row_step<false><<<8192, 256, 0, stream>>>(g, nullptr, t);
    col_step<<<512, 256, 0, stream>>>(g, t, v);
    for (int it = 1; it < 20; it++) {
        row_step<true><<<8192, 256, 0, stream>>>(g, v, t);
        col_step<<<512, 256, 0, stream>>>(g, t, v);
    }
    finalize_k<<<32768, 256, 0, stream>>>(g, t, v, out);
}

// Round 2
// 718.384 us; speedup vs baseline: 1.7084x; 1.7084x over previous
//
#include <hip/hip_runtime.h>
#include <hip/hip_fp16.h>
#include <math.h>

// B=32, N=1024 Sinkhorn (20 iters). scores@W+b cancels under the first row-lse
// -> inputs 0..2 dead. Linear domain: K' = exp(g - 8) (fp16, scale-invariant),
// u_i = 1/(K' v)_i, v_j = 1/(K'^T u)_j, out = K' .* (u v^T).
#define BB 32
#define NN 1024
#define SHIFT 8.0f

// ---------- main path (fp16 K in workspace) ----------

__global__ __launch_bounds__(256) void exp_rowsum(const float* __restrict__ g,
                                                  __half* __restrict__ K,
                                                  float* __restrict__ u) {
    const int wave = threadIdx.x >> 6, lane = threadIdx.x & 63;
    const int row = blockIdx.x * 4 + wave;               // b*N + i
    const float4* grow = (const float4*)(g + ((size_t)row << 10));
    uint2* krow = (uint2*)(K + ((size_t)row << 10));
    float s = 0.f;
    #pragma unroll
    for (int k = 0; k < 4; k++) {
        float4 gg = grow[lane + 64 * k];
        float e0 = __expf(gg.x - SHIFT), e1 = __expf(gg.y - SHIFT);
        float e2 = __expf(gg.z - SHIFT), e3 = __expf(gg.w - SHIFT);
        s += (e0 + e1) + (e2 + e3);
        __half2 h0 = __floats2half2_rn(e0, e1);
        __half2 h1 = __floats2half2_rn(e2, e3);
        uint2 pk;
        pk.x = *(unsigned int*)&h0;
        pk.y = *(unsigned int*)&h1;
        krow[lane + 64 * k] = pk;
    }
    #pragma unroll
    for (int off = 32; off; off >>= 1) s += __shfl_xor(s, off);
    if (lane == 0) u[row] = 1.0f / s;
}

// v_j = 1 / sum_i K[b,i,j] * u[b,i]
__global__ __launch_bounds__(1024) void col_pass(const __half* __restrict__ K,
                                                 const float* __restrict__ u,
                                                 float* __restrict__ v) {
    const int b = blockIdx.x >> 3, tile = blockIdx.x & 7;
    const int tx = threadIdx.x & 63, ty = threadIdx.x >> 6;   // ty 0..15
    const __half2* Kh = (const __half2*)(K + ((size_t)b << 20)) + tile * 64 + tx;
    const float* ub = u + (b << 10);
    float2 acc[8];
    #pragma unroll
    for (int q = 0; q < 8; q++) { acc[q].x = 0.f; acc[q].y = 0.f; }
    for (int k = 0; k < 64; k += 8) {
        #pragma unroll
        for (int q = 0; q < 8; q++) {
            int i = ((k + q) << 4) + ty;                      // i = 16*(k+q)+ty
            float2 f = __half22float2(Kh[(size_t)i << 9]);    // i*512 half2/row
            float ui = ub[i];
            acc[q].x = fmaf(f.x, ui, acc[q].x);
            acc[q].y = fmaf(f.y, ui, acc[q].y);
        }
    }
    float2 a = acc[0];
    #pragma unroll
    for (int q = 1; q < 8; q++) { a.x += acc[q].x; a.y += acc[q].y; }
    __shared__ float2 sm[16][64];
    sm[ty][tx] = a;
    __syncthreads();
    for (int h = 8; h >= 1; h >>= 1) {
        if (ty < h) {
            sm[ty][tx].x += sm[ty + h][tx].x;
            sm[ty][tx].y += sm[ty + h][tx].y;
        }
        __syncthreads();
    }
    if (ty == 0) {
        float2 c = sm[0][tx];
        ((float2*)(v + (b << 10)))[tile * 64 + tx] = make_float2(1.0f / c.x, 1.0f / c.y);
    }
}

// u_i = 1 / sum_j K[b,i,j] * v[b,j]
__global__ __launch_bounds__(256) void row_pass(const __half* __restrict__ K,
                                                const float* __restrict__ v,
                                                float* __restrict__ u) {
    const int wave = threadIdx.x >> 6, lane = threadIdx.x & 63;
    const int row = blockIdx.x * 4 + wave;
    const int b = row >> 10;
    const uint2* krow = (const uint2*)(K + ((size_t)row << 10));
    const float4* vrow = (const float4*)(v + ((size_t)b << 10));
    float s = 0.f;
    #pragma unroll
    for (int k = 0; k < 4; k++) {
        uint2 pk = krow[lane + 64 * k];
        __half2 h0 = *(__half2*)&pk.x, h1 = *(__half2*)&pk.y;
        float2 f0 = __half22float2(h0), f1 = __half22float2(h1);
        float4 vv = vrow[lane + 64 * k];
        s += f0.x * vv.x + f0.y * vv.y + f1.x * vv.z + f1.y * vv.w;
    }
    #pragma unroll
    for (int off = 32; off; off >>= 1) s += __shfl_xor(s, off);
    if (lane == 0) u[row] = 1.0f / s;
}

__global__ __launch_bounds__(256) void fin_pass(const __half* __restrict__ K,
                                                const float* __restrict__ u,
                                                const float* __restrict__ v,
                                                float* __restrict__ out) {
    const size_t idx4 = (size_t)blockIdx.x * 256 + threadIdx.x;
    const size_t base = idx4 << 2;
    const int row = (int)(base >> 10), b = row >> 10;
    const int j4 = ((int)(base & 1023)) >> 2;
    uint2 pk = ((const uint2*)K)[idx4];
    __half2 h0 = *(__half2*)&pk.x, h1 = *(__half2*)&pk.y;
    float2 f0 = __half22float2(h0), f1 = __half22float2(h1);
    float ui = u[row];
    float4 vv = ((const float4*)(v + ((size_t)b << 10)))[j4];
    float4 o;
    o.x = f0.x * ui * vv.x;
    o.y = f0.y * ui * vv.y;
    o.z = f1.x * ui * vv.z;
    o.w = f1.y * ui * vv.w;
    ((float4*)out)[idx4] = o;
}

// ---------- fallback path (round-1, log-domain, tiny ws) ----------

template<bool USE_V>
__global__ __launch_bounds__(256) void row_step(const float* __restrict__ g,
                                                const float* __restrict__ v,
                                                float* __restrict__ t) {
    const int wave = threadIdx.x >> 6, lane = threadIdx.x & 63;
    const int row = blockIdx.x * 4 + wave;
    const int b = row >> 10;
    const float4* grow = (const float4*)(g + ((size_t)row << 10));
    const float4* vrow = (const float4*)(v + ((size_t)b << 10));
    float x[16];
    #pragma unroll
    for (int k = 0; k < 4; k++) {
        float4 gg = grow[lane + 64 * k];
        if (USE_V) {
            float4 vv = vrow[lane + 64 * k];
            x[4*k+0] = gg.x + vv.x; x[4*k+1] = gg.y + vv.y;
            x[4*k+2] = gg.z + vv.z; x[4*k+3] = gg.w + vv.w;
        } else {
            x[4*k+0] = gg.x; x[4*k+1] = gg.y; x[4*k+2] = gg.z; x[4*k+3] = gg.w;
        }
    }
    float m = -INFINITY;
    #pragma unroll
    for (int k = 0; k < 16; k++) m = fmaxf(m, x[k]);
    #pragma unroll
    for (int off = 32; off; off >>= 1) m = fmaxf(m, __shfl_xor(m, off));
    float s = 0.f;
    #pragma unroll
    for (int k = 0; k < 16; k++) s += __expf(x[k] - m);
    #pragma unroll
    for (int off = 32; off; off >>= 1) s += __shfl_xor(s, off);
    if (lane == 0) t[row] = -(m + __logf(s));
}

__global__ __launch_bounds__(256) void col_step(const float* __restrict__ g,
                                                const float* __restrict__ t,
                                                float* __restrict__ v) {
    const int b = blockIdx.x >> 4, tile = blockIdx.x & 15;
    const int tx = threadIdx.x & 63, ty = threadIdx.x >> 6;
    const int j = tile * 64 + tx;
    const float* gp = g + ((size_t)b << 20) + j;
    const float* tp = t + (b << 10);
    float m = -INFINITY, s = 0.f;
    for (int it = 0; it < 256; it += 8) {
        float xv[8];
        #pragma unroll
        for (int u2 = 0; u2 < 8; u2++) {
            int i = ((it + u2) << 2) + ty;
            xv[u2] = gp[(size_t)i << 10] + tp[i];
        }
        #pragma unroll
        for (int u2 = 0; u2 < 8; u2++) {
            float nm = fmaxf(m, xv[u2]);
            s = s * __expf(m - nm) + __expf(xv[u2] - nm);
            m = nm;
        }
    }
    __shared__ float sm[4][64];
    __shared__ float ss[4][64];
    sm[ty][tx] = m; ss[ty][tx] = s;
    __syncthreads();
    if (ty == 0) {
        float M = sm[0][tx], S = ss[0][tx];
        #pragma unroll
        for (int k = 1; k < 4; k++) {
            float mk = sm[k][tx], sk = ss[k][tx];
            float nm = fmaxf(M, mk);
            S = S * __expf(M - nm) + sk * __expf(mk - nm);
            M = nm;
        }
        v[(b << 10) + j] = -(M + __logf(S));
    }
}

__global__ __launch_bounds__(256) void finalize_k(const float* __restrict__ g,
                                                  const float* __restrict__ t,
                                                  const float* __restrict__ v,
                                                  float* __restrict__ out) {
    const size_t idx4 = (size_t)blockIdx.x * 256 + threadIdx.x;
    const size_t base = idx4 << 2;
    const int row = (int)(base >> 10), b = row >> 10;
    const int j = (int)(base & 1023);
    const float ti = t[row];
    float4 gg = ((const float4*)g)[idx4];
    float4 vv = ((const float4*)(v + ((size_t)b << 10)))[j >> 2];
    float4 o;
    o.x = __expf(gg.x + ti + vv.x);
    o.y = __expf(gg.y + ti + vv.y);
    o.z = __expf(gg.z + ti + vv.z);
    o.w = __expf(gg.w + ti + vv.w);
    ((float4*)out)[idx4] = o;
}

extern "C" void kernel_launch(void* const* d_in, const int* in_sizes, int n_in,
                              void* d_out, int out_size, void* d_ws, size_t ws_size,
                              hipStream_t stream) {
    const float* g = (const float*)d_in[3];   // gumbel noise; inputs 0..2 dead
    float* out = (float*)d_out;
    const size_t needVec = 2ull * BB * NN * sizeof(float);          // 256 KB
    const size_t needK   = (size_t)BB * NN * NN * sizeof(__half);   // 67.1 MB

    if (ws_size >= needVec + needK) {
        float* u = (float*)d_ws;
        float* v = u + BB * NN;
        __half* K = (__half*)((char*)d_ws + needVec);
        exp_rowsum<<<8192, 256, 0, stream>>>(g, K, u);    // row step 1 + build K
        col_pass<<<256, 1024, 0, stream>>>(K, u, v);      // col step 1
        for (int it = 1; it < 20; it++) {
            row_pass<<<8192, 256, 0, stream>>>(K, v, u);
            col_pass<<<256, 1024, 0, stream>>>(K, u, v);
        }
        fin_pass<<<32768, 256, 0, stream>>>(K, u, v, out);
    } else {
        float* t = (float*)d_ws;
        float* v = t + BB * NN;
        row_step<false><<<8192, 256, 0, stream>>>(g, nullptr, t);
        col_step<<<512, 256, 0, stream>>>(g, t, v);
        for (int it = 1; it < 20; it++) {
            row_step<true><<<8192, 256, 0, stream>>>(g, v, t);
            col_step<<<512, 256, 0, stream>>>(g, t, v);
        }
        finalize_k<<<32768, 256, 0, stream>>>(g, t, v, out);
    }
}